// Round 1
// baseline (451.730 us; speedup 1.0000x reference)
//
#include <hip/hip_runtime.h>

#define N_NODES 50000
#define N_EDGES 800000

// ws layout (in floats):
//  [400000, 404096)   consts[k][32]
//  [404096, 404104)   scalars: {c, ce, wde0, wde1, wde2, ...}
//  [404608, ...)      part[copy][node][8]  (es0,es1,es2,cnt_s, er0,er1,er2,cnt_r)
#define CONSTS_OFF 400000
#define SCAL_OFF   404096
#define PART_OFF   404608
#define NCOPY_MAX  8
#define ZERO_BLOCKS 512

__global__ void precompute_kernel(
    const float* __restrict__ g,      // globals_ [8]
    const float* __restrict__ W_en,   // [16][128]
    const float* __restrict__ b_en,   // [128]
    const float* __restrict__ W_ee,   // [3][128]
    const float* __restrict__ b_ee,   // [128]
    const float* __restrict__ W1,     // [392][128]
    const float* __restrict__ b1,     // [128]
    const float* __restrict__ W2,     // [128][128]
    const float* __restrict__ b2,     // [128]
    const float* __restrict__ W_dn,   // [128]
    const float* __restrict__ b_dn,   // [1]
    const float* __restrict__ W_de,   // [128]
    const float* __restrict__ b_de,   // [1]
    float* __restrict__ ws,
    int ncopy)
{
    const int s = blockIdx.x;
    const int k = threadIdx.x;
    float* consts = ws + CONSTS_OFF;
    float* scal   = ws + SCAL_OFF;

    if (s >= 27) {
        // zero the privatized part buffers: ncopy * N_NODES * 8 floats
        float4* p = (float4*)(ws + PART_OFF);
        const long tot4 = (long)ncopy * N_NODES * 2;   // float4 count
        const long stride = (long)(gridDim.x - 27) * 128;
        for (long i = (long)(s - 27) * 128 + k; i < tot4; i += stride)
            p[i] = make_float4(0.f, 0.f, 0.f, 0.f);
        return;
    }

    if (s < 16) {
        float acc = 0.f;
        for (int l = 0; l < 128; ++l)
            acc += W_en[s * 128 + l] * W1[l * 128 + k];
        consts[k * 32 + s] = acc;
    } else if (s < 19) {
        const int j = s - 16;
        float acc = 0.f;
        for (int l = 0; l < 128; ++l)
            acc += W_ee[j * 128 + l] * W1[(128 + l) * 128 + k];
        consts[k * 32 + s] = acc;
    } else if (s < 22) {
        const int j = s - 19;
        float acc = 0.f;
        for (int l = 0; l < 128; ++l)
            acc += W_ee[j * 128 + l] * W1[(256 + l) * 128 + k];
        consts[k * 32 + s] = acc;
    } else if (s == 22) {
        float acc = b1[k];
        for (int l = 0; l < 128; ++l)
            acc += b_en[l] * W1[l * 128 + k];
        for (int j = 0; j < 8; ++j)
            acc += g[j] * W1[(384 + j) * 128 + k];
        consts[k * 32 + 22] = acc;
    } else if (s == 23) {
        float acc = 0.f;
        for (int l = 0; l < 128; ++l)
            acc += b_ee[l] * W1[(128 + l) * 128 + k];
        consts[k * 32 + 23] = acc;
    } else if (s == 24) {
        float acc = 0.f;
        for (int l = 0; l < 128; ++l)
            acc += b_ee[l] * W1[(256 + l) * 128 + k];
        consts[k * 32 + 24] = acc;
    } else if (s == 25) {
        float acc = 0.f;
        for (int j = 0; j < 128; ++j)
            acc += W2[k * 128 + j] * W_dn[j];
        consts[k * 32 + 25] = acc;
        consts[k * 32 + 26] = 0.f;
        consts[k * 32 + 27] = 0.f;
    } else {
        if (k == 0) {
            float c = b_dn[0];
            for (int j = 0; j < 128; ++j) c += b2[j] * W_dn[j];
            scal[0] = c;
            float ce = b_de[0];
            for (int l = 0; l < 128; ++l) ce += b_ee[l] * W_de[l];
            scal[1] = ce;
            scal[5] = 0.f; scal[6] = 0.f; scal[7] = 0.f;
        }
        if (k < 3) {
            float acc = 0.f;
            for (int l = 0; l < 128; ++l)
                acc += W_ee[k * 128 + l] * W_de[l];
            scal[2 + k] = acc;
        }
    }
}

// Single-pass fused kernel: reads edges+indices exactly once, writes the edge
// decoder output, and scatters segment sums via HW f32 atomics into one of
// `ncopy` privatized accumulator copies (copy = blockIdx % ncopy, which tracks
// the round-robin block->XCD mapping so each copy stays L2-local).
// Atomics are fire-and-forget (result unused) -> no vmcnt stall in the wave.
__global__ __launch_bounds__(256) void scatter_kernel(
    const float* __restrict__ edges,      // [E][3]
    const int*   __restrict__ senders,    // [E]
    const int*   __restrict__ receivers,  // [E]
    const float* __restrict__ ws,
    float* __restrict__ part,             // [ncopy][N_NODES][8]
    float* __restrict__ out_edges,        // [E]
    int ncopy)
{
    const int t  = blockIdx.x * 256 + threadIdx.x;
    const int e8 = t * 8;
    if (e8 >= N_EDGES) return;

    const float* scal = ws + SCAL_OFF;
    const float w0 = scal[2], w1 = scal[3], w2 = scal[4], cb = scal[1];

    const int4 sa = *(const int4*)(senders + e8);
    const int4 sb = *(const int4*)(senders + e8 + 4);
    const int4 ra = *(const int4*)(receivers + e8);
    const int4 rb = *(const int4*)(receivers + e8 + 4);

    const float4* ep = (const float4*)(edges + (size_t)e8 * 3);
    const float4 f0 = ep[0], f1 = ep[1], f2 = ep[2];
    const float4 f3 = ep[3], f4 = ep[4], f5 = ep[5];

    // fused edge decoder output
    float4 oa, ob;
    oa.x = fmaf(f0.x, w0, fmaf(f0.y, w1, fmaf(f0.z, w2, cb)));
    oa.y = fmaf(f0.w, w0, fmaf(f1.x, w1, fmaf(f1.y, w2, cb)));
    oa.z = fmaf(f1.z, w0, fmaf(f1.w, w1, fmaf(f2.x, w2, cb)));
    oa.w = fmaf(f2.y, w0, fmaf(f2.z, w1, fmaf(f2.w, w2, cb)));
    ob.x = fmaf(f3.x, w0, fmaf(f3.y, w1, fmaf(f3.z, w2, cb)));
    ob.y = fmaf(f3.w, w0, fmaf(f4.x, w1, fmaf(f4.y, w2, cb)));
    ob.z = fmaf(f4.z, w0, fmaf(f4.w, w1, fmaf(f5.x, w2, cb)));
    ob.w = fmaf(f5.y, w0, fmaf(f5.z, w1, fmaf(f5.w, w2, cb)));
    *(float4*)(out_edges + e8)     = oa;
    *(float4*)(out_edges + e8 + 4) = ob;

    float* base = part + (size_t)(blockIdx.x % ncopy) * (N_NODES * 8);

#define SCAT(sidx, ridx, a, b, c) do {                                  \
        float* ps = base + (size_t)(sidx) * 8;                          \
        unsafeAtomicAdd(ps + 0, (a)); unsafeAtomicAdd(ps + 1, (b));     \
        unsafeAtomicAdd(ps + 2, (c)); unsafeAtomicAdd(ps + 3, 1.0f);    \
        float* pr = base + (size_t)(ridx) * 8 + 4;                      \
        unsafeAtomicAdd(pr + 0, (a)); unsafeAtomicAdd(pr + 1, (b));     \
        unsafeAtomicAdd(pr + 2, (c)); unsafeAtomicAdd(pr + 3, 1.0f);    \
    } while (0)

    SCAT(sa.x, ra.x, f0.x, f0.y, f0.z);
    SCAT(sa.y, ra.y, f0.w, f1.x, f1.y);
    SCAT(sa.z, ra.z, f1.z, f1.w, f2.x);
    SCAT(sa.w, ra.w, f2.y, f2.z, f2.w);
    SCAT(sb.x, rb.x, f3.x, f3.y, f3.z);
    SCAT(sb.y, rb.y, f3.w, f4.x, f4.y);
    SCAT(sb.z, rb.z, f4.z, f4.w, f5.x);
    SCAT(sb.w, rb.w, f5.y, f5.z, f5.w);
#undef SCAT
}

// Node MLP. Consts are read with wave-uniform addresses straight from global
// memory (scalar s_load path). Sums the ncopy privatized aggregate copies.
__global__ __launch_bounds__(64) void node_kernel(
    const float* __restrict__ nodes,  // [N][16]
    const float* __restrict__ ws,
    const float* __restrict__ part,   // [ncopy][N_NODES][8]
    float* __restrict__ out_nodes,
    int ncopy)
{
    const int n = blockIdx.x * 64 + threadIdx.x;
    if (n >= N_NODES) return;

    const float4* np4 = (const float4*)(nodes + (size_t)n * 16);
    const float4 n0 = np4[0], n1 = np4[1], n2 = np4[2], n3 = np4[3];

    float4 es = make_float4(0.f, 0.f, 0.f, 0.f);
    float4 er = make_float4(0.f, 0.f, 0.f, 0.f);
    for (int c = 0; c < ncopy; ++c) {
        const float4* p = (const float4*)(part + (size_t)c * (N_NODES * 8) + (size_t)n * 8);
        const float4 a = p[0], b = p[1];
        es.x += a.x; es.y += a.y; es.z += a.z; es.w += a.w;
        er.x += b.x; er.y += b.y; er.z += b.z; er.w += b.w;
    }

    const float* cst = ws + CONSTS_OFF;  // wave-uniform reads
    float acc = 0.f;
#pragma unroll 4
    for (int k = 0; k < 128; ++k) {
        const float4 m0 = *(const float4*)(cst + k * 32 + 0);
        const float4 m1 = *(const float4*)(cst + k * 32 + 4);
        const float4 m2 = *(const float4*)(cst + k * 32 + 8);
        const float4 m3 = *(const float4*)(cst + k * 32 + 12);
        const float4 q0 = *(const float4*)(cst + k * 32 + 16);
        const float4 q1 = *(const float4*)(cst + k * 32 + 20);
        const float4 q2 = *(const float4*)(cst + k * 32 + 24);
        float pre = q1.z
            + n0.x * m0.x + n0.y * m0.y + n0.z * m0.z + n0.w * m0.w
            + n1.x * m1.x + n1.y * m1.y + n1.z * m1.z + n1.w * m1.w
            + n2.x * m2.x + n2.y * m2.y + n2.z * m2.z + n2.w * m2.w
            + n3.x * m3.x + n3.y * m3.y + n3.z * m3.z + n3.w * m3.w
            + es.x * q0.x + es.y * q0.y + es.z * q0.z
            + er.x * q0.w + er.y * q1.x + er.z * q1.y
            + es.w * q1.w + er.w * q2.x;
        acc += fmaxf(pre, 0.f) * q2.y;
    }
    const float* scal = ws + SCAL_OFF;
    out_nodes[n] = acc + scal[0];
}

extern "C" void kernel_launch(void* const* d_in, const int* in_sizes, int n_in,
                              void* d_out, int out_size, void* d_ws, size_t ws_size,
                              hipStream_t stream) {
    const float* nodes     = (const float*)d_in[0];
    const float* edges     = (const float*)d_in[1];
    const float* globals_  = (const float*)d_in[2];
    const int*   senders   = (const int*)d_in[3];
    const int*   receivers = (const int*)d_in[4];
    const float* W_en = (const float*)d_in[5];
    const float* b_en = (const float*)d_in[6];
    const float* W_ee = (const float*)d_in[7];
    const float* b_ee = (const float*)d_in[8];
    const float* W1   = (const float*)d_in[9];
    const float* b1   = (const float*)d_in[10];
    const float* W2   = (const float*)d_in[11];
    const float* b2   = (const float*)d_in[12];
    const float* W_dn = (const float*)d_in[13];
    const float* b_dn = (const float*)d_in[14];
    const float* W_de = (const float*)d_in[15];
    const float* b_de = (const float*)d_in[16];

    float* ws  = (float*)d_ws;
    float* out = (float*)d_out;

    long ws_floats = (long)(ws_size / 4);
    long avail = (ws_floats - PART_OFF) / ((long)N_NODES * 8);
    int ncopy = (int)(avail < 1 ? 1 : (avail > NCOPY_MAX ? NCOPY_MAX : avail));

    float* part = ws + PART_OFF;

    // precompute consts + zero the part buffers (fused grid)
    precompute_kernel<<<27 + ZERO_BLOCKS, 128, 0, stream>>>(
        globals_, W_en, b_en, W_ee, b_ee, W1, b1, W2, b2,
        W_dn, b_dn, W_de, b_de, ws, ncopy);

    // single-pass: edge decoder + privatized-atomic aggregation
    scatter_kernel<<<(N_EDGES / 8 + 255) / 256, 256, 0, stream>>>(
        edges, senders, receivers, ws, part, out + N_NODES, ncopy);

    // node MLP + copy reduction
    node_kernel<<<(N_NODES + 63) / 64, 64, 0, stream>>>(
        nodes, ws, part, out, ncopy);
}

// Round 3
// 171.061 us; speedup vs baseline: 2.6407x; 2.6407x over previous
//
#include <hip/hip_runtime.h>

#define N_NODES 50000
#define N_EDGES 800000

// ws layout (in floats):
//  [0, 400000)        esr[node][8] (fallback path only)
//  [400000, 404096)   consts[k][32]
//  [404096, 404104)   scalars: {c, ce, wde0, wde1, wde2, pad...}
//  [404608, ...)      part_s[c][node][4] then part_r[c][node][4]
#define ESR_OFF    0
#define CONSTS_OFF 400000
#define SCAL_OFF   404096
#define PART_OFF   404608

#define NBINS      25
#define BINSZ      2000   // nodes per bin-side; LDS = 2000*4*4 = 32000 B; 4 blocks/CU
#define MAX_CHUNKS 20

// Latency-optimized precompute: 512 threads/block, every 128-deep reduction
// split 4 ways (k = tid&127, lh = tid>>7 owns a 32-wide l-slice), combined
// through LDS. Cuts the per-output serial load chain 128 -> 32 and raises
// waves/block 2 -> 8.
__global__ __launch_bounds__(512) void precompute_kernel(
    const float* __restrict__ g,      // globals_ [8]
    const float* __restrict__ W_en,   // [16][128]
    const float* __restrict__ b_en,   // [128]
    const float* __restrict__ W_ee,   // [3][128]
    const float* __restrict__ b_ee,   // [128]
    const float* __restrict__ W1,     // [392][128]
    const float* __restrict__ b1,     // [128]
    const float* __restrict__ W2,     // [128][128]
    const float* __restrict__ b2,     // [128]
    const float* __restrict__ W_dn,   // [128]
    const float* __restrict__ b_dn,   // [1]
    const float* __restrict__ W_de,   // [128]
    const float* __restrict__ b_de,   // [1]
    float* __restrict__ ws)
{
    const int s  = blockIdx.x;
    const int t  = threadIdx.x;
    const int k  = t & 127;
    const int lh = t >> 7;            // 0..3
    float* consts = ws + CONSTS_OFF;
    float* scal   = ws + SCAL_OFF;

    __shared__ float red[512];

    if (s < 25) {
        // consts[k][s] = sum_l lhs[l] * W1[(off+l)*128 + k]   (128-deep)
        // s<16:   lhs = W_en[s][:],   off = 0
        // 16..18: lhs = W_ee[s-16][:], off = 128
        // 19..21: lhs = W_ee[s-19][:], off = 256
        // 22:     lhs = b_en[:],      off = 0    (+ b1[k] + g-terms)
        // 23:     lhs = b_ee[:],      off = 128
        // 24:     lhs = b_ee[:],      off = 256
        const float* lhs;
        int off;
        if (s < 16)      { lhs = W_en + s * 128;        off = 0;   }
        else if (s < 19) { lhs = W_ee + (s - 16) * 128; off = 128; }
        else if (s < 22) { lhs = W_ee + (s - 19) * 128; off = 256; }
        else if (s == 22){ lhs = b_en;                  off = 0;   }
        else if (s == 23){ lhs = b_ee;                  off = 128; }
        else             { lhs = b_ee;                  off = 256; }

        float acc = 0.f;
        const int l0 = lh * 32;
#pragma unroll
        for (int u = 0; u < 32; ++u) {
            const int l = l0 + u;
            acc += lhs[l] * W1[(off + l) * 128 + k];
        }
        red[t] = acc;
        __syncthreads();
        if (lh == 0) {
            float v = red[k] + red[k + 128] + red[k + 256] + red[k + 384];
            if (s == 22) {
                v += b1[k];
#pragma unroll
                for (int j = 0; j < 8; ++j)
                    v += g[j] * W1[(384 + j) * 128 + k];
            }
            consts[k * 32 + s] = v;
        }
    } else if (s == 25) {
        // consts[k][25] = sum_j W2[k][j] * W_dn[j]; each thread reads 32
        // consecutive floats of row k (cache-line friendly).
        float acc = 0.f;
        const int j0 = lh * 32;
#pragma unroll
        for (int u = 0; u < 32; ++u)
            acc += W2[k * 128 + j0 + u] * W_dn[j0 + u];
        red[t] = acc;
        __syncthreads();
        if (lh == 0) {
            consts[k * 32 + 25] = red[k] + red[k + 128] + red[k + 256] + red[k + 384];
            consts[k * 32 + 26] = 0.f;
            consts[k * 32 + 27] = 0.f;
        }
    } else {
        // scalars. phase 1: four 128-wide products in parallel ranges.
        float v = 0.f;
        if (t < 128)       v = b2[t] * W_dn[t];              // -> scal[0]
        else if (t < 256)  v = b_ee[t - 128] * W_de[t - 128]; // -> scal[1]
        else if (t < 384)  v = W_ee[0 * 128 + (t - 256)] * W_de[t - 256]; // scal[2]
        else               v = W_ee[1 * 128 + (t - 384)] * W_de[t - 384]; // scal[3]
        red[t] = v;
        __syncthreads();
        // tree-reduce each 128-range
        for (int w = 64; w > 0; w >>= 1) {
            if ((t & 127) < w) red[t] += red[t + w];
            __syncthreads();
        }
        if (t == 0)   scal[0] = red[0]   + b_dn[0];
        if (t == 128) scal[1] = red[128] + b_de[0];
        if (t == 256) scal[2] = red[256];
        if (t == 384) scal[3] = red[384];
        __syncthreads();
        // phase 2: W_ee[2]·W_de
        float v2 = (t < 128) ? W_ee[2 * 128 + t] * W_de[t] : 0.f;
        red[t] = v2;
        __syncthreads();
        for (int w = 64; w > 0; w >>= 1) {
            if (t < w) red[t] += red[t + w];
            __syncthreads();
        }
        if (t == 0) { scal[4] = red[0]; scal[5] = 0.f; scal[6] = 0.f; scal[7] = 0.f; }
    }
}

// Pure streaming edge decoder.
__global__ __launch_bounds__(256) void edge_out_kernel(
    const float* __restrict__ edges,
    const float* __restrict__ ws,
    float* __restrict__ out_edges)
{
    const int e4 = (blockIdx.x * 256 + threadIdx.x) * 4;
    if (e4 >= N_EDGES) return;
    const float* scal = ws + SCAL_OFF;
    const float w0 = scal[2], w1 = scal[3], w2 = scal[4], cb = scal[1];
    const float4* ep = (const float4*)(edges + (size_t)e4 * 3);
    const float4 f0 = ep[0], f1 = ep[1], f2 = ep[2];
    float4 o;
    o.x = fmaf(f0.x, w0, fmaf(f0.y, w1, fmaf(f0.z, w2, cb)));
    o.y = fmaf(f0.w, w0, fmaf(f1.x, w1, fmaf(f1.y, w2, cb)));
    o.z = fmaf(f1.z, w0, fmaf(f1.w, w1, fmaf(f2.x, w2, cb)));
    o.w = fmaf(f2.y, w0, fmaf(f2.z, w1, fmaf(f2.w, w2, cb)));
    *(float4*)(out_edges + e4) = o;
}

// Split-side binned aggregation, 32KB LDS -> 4 blocks/CU (32 waves/CU),
// 8 edges/thread with 1-deep index prefetch pipeline. (R0-proven.)
__global__ __launch_bounds__(512, 8) void agg_kernel(
    const float* __restrict__ edges,     // [E][3]
    const int*   __restrict__ senders,   // [E]
    const int*   __restrict__ receivers, // [E]
    float* __restrict__ part_s,          // [nchunks][N_NODES][4]
    float* __restrict__ part_r,          // [nchunks][N_NODES][4]
    int ce)                              // edges per chunk (multiple of 8)
{
    __shared__ float4 acc4[BINSZ];       // [BINSZ][4] floats = 32000 B
    float* acc = (float*)acc4;
    const int tid = threadIdx.x;
    for (int i = tid; i < BINSZ; i += 512)
        acc4[i] = make_float4(0.f, 0.f, 0.f, 0.f);
    __syncthreads();

    const int chunk  = blockIdx.x;
    const int binid  = blockIdx.y;
    const bool is_s  = binid < NBINS;
    const int bin    = is_s ? binid : binid - NBINS;
    const int lo     = bin * BINSZ;
    const int* __restrict__ idx = is_s ? senders : receivers;

    const int e_beg = chunk * ce;
    const int e_end = min(e_beg + ce, N_EDGES);
    const int STRIDE = 512 * 8;

    int e8 = e_beg + tid * 8;
    int4 ia = make_int4(-1, -1, -1, -1), ib = ia;
    if (e8 < e_end) {
        ia = *(const int4*)(idx + e8);
        ib = *(const int4*)(idx + e8 + 4);
    }
    while (e8 < e_end) {
        const int e8n = e8 + STRIDE;
        int4 ian = ia, ibn = ib;
        if (e8n < e_end) {                    // prefetch next iteration's indices
            ian = *(const int4*)(idx + e8n);
            ibn = *(const int4*)(idx + e8n + 4);
        }
        const unsigned d0 = (unsigned)(ia.x - lo), d1 = (unsigned)(ia.y - lo);
        const unsigned d2 = (unsigned)(ia.z - lo), d3 = (unsigned)(ia.w - lo);
        const unsigned d4 = (unsigned)(ib.x - lo), d5 = (unsigned)(ib.y - lo);
        const unsigned d6 = (unsigned)(ib.z - lo), d7 = (unsigned)(ib.w - lo);
        if ((d0 < BINSZ) | (d1 < BINSZ) | (d2 < BINSZ) | (d3 < BINSZ)) {
            const float4* ep = (const float4*)(edges + (size_t)e8 * 3);
            const float4 f0 = ep[0], f1 = ep[1], f2 = ep[2];
            // e0: f0.x f0.y f0.z | e1: f0.w f1.x f1.y | e2: f1.z f1.w f2.x | e3: f2.y f2.z f2.w
            if (d0 < BINSZ) {
                atomicAdd(&acc[d0 * 4 + 0], f0.x); atomicAdd(&acc[d0 * 4 + 1], f0.y);
                atomicAdd(&acc[d0 * 4 + 2], f0.z); atomicAdd(&acc[d0 * 4 + 3], 1.0f);
            }
            if (d1 < BINSZ) {
                atomicAdd(&acc[d1 * 4 + 0], f0.w); atomicAdd(&acc[d1 * 4 + 1], f1.x);
                atomicAdd(&acc[d1 * 4 + 2], f1.y); atomicAdd(&acc[d1 * 4 + 3], 1.0f);
            }
            if (d2 < BINSZ) {
                atomicAdd(&acc[d2 * 4 + 0], f1.z); atomicAdd(&acc[d2 * 4 + 1], f1.w);
                atomicAdd(&acc[d2 * 4 + 2], f2.x); atomicAdd(&acc[d2 * 4 + 3], 1.0f);
            }
            if (d3 < BINSZ) {
                atomicAdd(&acc[d3 * 4 + 0], f2.y); atomicAdd(&acc[d3 * 4 + 1], f2.z);
                atomicAdd(&acc[d3 * 4 + 2], f2.w); atomicAdd(&acc[d3 * 4 + 3], 1.0f);
            }
        }
        if ((d4 < BINSZ) | (d5 < BINSZ) | (d6 < BINSZ) | (d7 < BINSZ)) {
            const float4* ep = (const float4*)(edges + (size_t)e8 * 3 + 12);
            const float4 f0 = ep[0], f1 = ep[1], f2 = ep[2];
            if (d4 < BINSZ) {
                atomicAdd(&acc[d4 * 4 + 0], f0.x); atomicAdd(&acc[d4 * 4 + 1], f0.y);
                atomicAdd(&acc[d4 * 4 + 2], f0.z); atomicAdd(&acc[d4 * 4 + 3], 1.0f);
            }
            if (d5 < BINSZ) {
                atomicAdd(&acc[d5 * 4 + 0], f0.w); atomicAdd(&acc[d5 * 4 + 1], f1.x);
                atomicAdd(&acc[d5 * 4 + 2], f1.y); atomicAdd(&acc[d5 * 4 + 3], 1.0f);
            }
            if (d6 < BINSZ) {
                atomicAdd(&acc[d6 * 4 + 0], f1.z); atomicAdd(&acc[d6 * 4 + 1], f1.w);
                atomicAdd(&acc[d6 * 4 + 2], f2.x); atomicAdd(&acc[d6 * 4 + 3], 1.0f);
            }
            if (d7 < BINSZ) {
                atomicAdd(&acc[d7 * 4 + 0], f2.y); atomicAdd(&acc[d7 * 4 + 1], f2.z);
                atomicAdd(&acc[d7 * 4 + 2], f2.w); atomicAdd(&acc[d7 * 4 + 3], 1.0f);
            }
        }
        ia = ian; ib = ibn;
        e8 = e8n;
    }
    __syncthreads();

    float* base = (is_s ? part_s : part_r) + (size_t)chunk * (N_NODES * 4) + (size_t)lo * 4;
    float4* dst = (float4*)base;
    for (int i = tid; i < BINSZ; i += 512)
        dst[i] = acc4[i];
}

// ---- fallback path (tiny ws): global-atomic scatter into esr[node][8] ----
__global__ __launch_bounds__(256) void edge_kernel_atomic(
    const float* __restrict__ edges,
    const int*   __restrict__ senders,
    const int*   __restrict__ receivers,
    float* __restrict__ ws)
{
    const int e = blockIdx.x * 256 + threadIdx.x;
    if (e >= N_EDGES) return;
    const float e0 = edges[e * 3 + 0];
    const float e1 = edges[e * 3 + 1];
    const float e2 = edges[e * 3 + 2];
    const int s = senders[e];
    const int r = receivers[e];
    float* esr = ws + ESR_OFF;
    atomicAdd(&esr[s * 8 + 0], e0);
    atomicAdd(&esr[s * 8 + 1], e1);
    atomicAdd(&esr[s * 8 + 2], e2);
    atomicAdd(&esr[s * 8 + 3], 1.0f);
    atomicAdd(&esr[r * 8 + 4], e0);
    atomicAdd(&esr[r * 8 + 5], e1);
    atomicAdd(&esr[r * 8 + 6], e2);
    atomicAdd(&esr[r * 8 + 7], 1.0f);
}

// Node MLP. Consts are read with wave-uniform addresses straight from global
// memory (scalar s_load path); FMAs take one SGPR operand.
__global__ __launch_bounds__(64) void node_kernel(
    const float* __restrict__ nodes,  // [N][16]
    const float* __restrict__ ws,
    const float* __restrict__ part_s,
    const float* __restrict__ part_r,
    float* __restrict__ out_nodes,    // d_out
    int nchunks)
{
    const int n = blockIdx.x * 64 + threadIdx.x;
    if (n >= N_NODES) return;

    const float4* np4 = (const float4*)(nodes + (size_t)n * 16);
    const float4 n0 = np4[0], n1 = np4[1], n2 = np4[2], n3 = np4[3];

    float4 es = make_float4(0.f, 0.f, 0.f, 0.f);
    float4 er = make_float4(0.f, 0.f, 0.f, 0.f);
    if (nchunks > 0) {
        for (int c = 0; c < nchunks; ++c) {
            const float4 a = *(const float4*)(part_s + (size_t)c * (N_NODES * 4) + (size_t)n * 4);
            const float4 b = *(const float4*)(part_r + (size_t)c * (N_NODES * 4) + (size_t)n * 4);
            es.x += a.x; es.y += a.y; es.z += a.z; es.w += a.w;
            er.x += b.x; er.y += b.y; er.z += b.z; er.w += b.w;
        }
    } else {
        const float4* p = (const float4*)(ws + ESR_OFF + (size_t)n * 8);
        es = p[0];
        er = p[1];
    }

    const float* cst = ws + CONSTS_OFF;  // wave-uniform reads below
    float acc = 0.f;
#pragma unroll 4
    for (int k = 0; k < 128; ++k) {
        const float4 m0 = *(const float4*)(cst + k * 32 + 0);
        const float4 m1 = *(const float4*)(cst + k * 32 + 4);
        const float4 m2 = *(const float4*)(cst + k * 32 + 8);
        const float4 m3 = *(const float4*)(cst + k * 32 + 12);
        const float4 q0 = *(const float4*)(cst + k * 32 + 16);
        const float4 q1 = *(const float4*)(cst + k * 32 + 20);
        const float4 q2 = *(const float4*)(cst + k * 32 + 24);
        float pre = q1.z
            + n0.x * m0.x + n0.y * m0.y + n0.z * m0.z + n0.w * m0.w
            + n1.x * m1.x + n1.y * m1.y + n1.z * m1.z + n1.w * m1.w
            + n2.x * m2.x + n2.y * m2.y + n2.z * m2.z + n2.w * m2.w
            + n3.x * m3.x + n3.y * m3.y + n3.z * m3.z + n3.w * m3.w
            + es.x * q0.x + es.y * q0.y + es.z * q0.z
            + er.x * q0.w + er.y * q1.x + er.z * q1.y
            + es.w * q1.w + er.w * q2.x;
        acc += fmaxf(pre, 0.f) * q2.y;
    }
    const float* scal = ws + SCAL_OFF;
    out_nodes[n] = acc + scal[0];
}

extern "C" void kernel_launch(void* const* d_in, const int* in_sizes, int n_in,
                              void* d_out, int out_size, void* d_ws, size_t ws_size,
                              hipStream_t stream) {
    const float* nodes     = (const float*)d_in[0];
    const float* edges     = (const float*)d_in[1];
    const float* globals_  = (const float*)d_in[2];
    const int*   senders   = (const int*)d_in[3];
    const int*   receivers = (const int*)d_in[4];
    const float* W_en = (const float*)d_in[5];
    const float* b_en = (const float*)d_in[6];
    const float* W_ee = (const float*)d_in[7];
    const float* b_ee = (const float*)d_in[8];
    const float* W1   = (const float*)d_in[9];
    const float* b1   = (const float*)d_in[10];
    const float* W2   = (const float*)d_in[11];
    const float* b2   = (const float*)d_in[12];
    const float* W_dn = (const float*)d_in[13];
    const float* b_dn = (const float*)d_in[14];
    const float* W_de = (const float*)d_in[15];
    const float* b_de = (const float*)d_in[16];

    float* ws = (float*)d_ws;
    float* out = (float*)d_out;

    precompute_kernel<<<27, 512, 0, stream>>>(
        globals_, W_en, b_en, W_ee, b_ee, W1, b1, W2, b2,
        W_dn, b_dn, W_de, b_de, ws);

    edge_out_kernel<<<(N_EDGES / 4 + 255) / 256, 256, 0, stream>>>(
        edges, ws, out + N_NODES);

    long ws_floats = (long)(ws_size / 4);
    long per_chunk = 2L * N_NODES * 4;  // part_s + part_r copies
    long avail = (ws_floats - PART_OFF) / per_chunk;
    int nchunks = (int)(avail < 0 ? 0 : (avail > MAX_CHUNKS ? MAX_CHUNKS : avail));

    float* part_s = ws + PART_OFF;
    float* part_r = part_s + (size_t)nchunks * (N_NODES * 4);

    if (nchunks >= 1) {
        int ce = (N_EDGES + nchunks - 1) / nchunks;
        ce = (ce + 7) & ~7;  // keep 8-edge groups int4-aligned
        dim3 grid(nchunks, 2 * NBINS);
        agg_kernel<<<grid, 512, 0, stream>>>(
            edges, senders, receivers, part_s, part_r, ce);
    } else {
        hipMemsetAsync(ws + ESR_OFF, 0, (size_t)N_NODES * 8 * sizeof(float), stream);
        edge_kernel_atomic<<<(N_EDGES + 255) / 256, 256, 0, stream>>>(
            edges, senders, receivers, ws);
    }

    node_kernel<<<(N_NODES + 63) / 64, 64, 0, stream>>>(
        nodes, ws, part_s, part_r, out, nchunks);
}

// Round 5
// 169.049 us; speedup vs baseline: 2.6722x; 1.0119x over previous
//
#include <hip/hip_runtime.h>

#define N_NODES 50000
#define N_EDGES 800000

// ws layout (in floats):
//  [0, 400000)        esr[node][8] (fallback path only)
//  [400000, 404096)   consts[k][32]   (consts[26] = c_node bias)
//  [404608, ...)      part_s[c][node][4] then part_r[c][node][4]
#define ESR_OFF    0
#define CONSTS_OFF 400000
#define PART_OFF   404608

#define NBINS   13
#define BINSZ   4096     // 13*4096 = 53248 >= 50000; LDS 65536 B -> 2 blocks/CU
#define MAXCH   19       // 26*19 = 494 blocks ~ 2 blocks/CU across 256 CUs

// Fused front kernel: per-block scalar consts (redundant, deterministic)
// -> consts GEMVs (blocks 0..25) -> edge decode (grid-stride)
// -> binned LDS-atomic aggregation -> partial writeback.
__global__ __launch_bounds__(512, 4) void front_kernel(
    const float* __restrict__ edges,     // [E][3]
    const float* __restrict__ g,         // [8]
    const int*   __restrict__ senders,   // [E]
    const int*   __restrict__ receivers, // [E]
    const float* __restrict__ W_en, const float* __restrict__ b_en,
    const float* __restrict__ W_ee, const float* __restrict__ b_ee,
    const float* __restrict__ W1,   const float* __restrict__ b1,
    const float* __restrict__ W2,   const float* __restrict__ b2,
    const float* __restrict__ W_dn, const float* __restrict__ b_dn,
    const float* __restrict__ W_de, const float* __restrict__ b_de,
    float* __restrict__ ws,
    float* __restrict__ out_edges,       // [E]
    int nch, int ce)
{
    __shared__ float4 acc4[BINSZ];          // 65536 B; first 2048 B reused as red[]
    float* red = (float*)acc4;
    float* acc = (float*)acc4;
    const int tid  = threadIdx.x;
    const int bid  = blockIdx.x;
    const int nblk = gridDim.x;

    // ---- per-block scalar constants ----
    float v = 0.f;
    if (tid < 128)      v = b2[tid] * W_dn[tid];                    // -> c_node
    else if (tid < 256) v = b_ee[tid - 128] * W_de[tid - 128];      // -> cb
    else if (tid < 384) v = W_ee[tid - 256] * W_de[tid - 256];      // -> w0
    else                v = W_ee[128 + tid - 384] * W_de[tid - 384];// -> w1
    red[tid] = v;
    __syncthreads();
    for (int w = 64; w > 0; w >>= 1) {
        if ((tid & 127) < w) red[tid] += red[tid + w];
        __syncthreads();
    }
    const float c_node = red[0]   + b_dn[0];
    const float cb     = red[128] + b_de[0];
    const float w0     = red[256];
    const float w1     = red[384];
    __syncthreads();
    float v2 = (tid < 128) ? W_ee[256 + tid] * W_de[tid] : 0.f;
    red[tid] = v2;
    __syncthreads();
    for (int w = 64; w > 0; w >>= 1) {
        if (tid < w) red[tid] += red[tid + w];
        __syncthreads();
    }
    const float w2 = red[0];
    __syncthreads();

    // ---- consts GEMV jobs: consts[k][s], s in [0,26) ----
    const int k  = tid & 127;
    const int lh = tid >> 7;     // 0..3, wave-uniform
    float* consts = ws + CONSTS_OFF;
    for (int s = bid; s < 26; s += nblk) {
        if (s < 25) {
            const float* lhs; int off;
            if (s < 16)      { lhs = W_en + s * 128;        off = 0;   }
            else if (s < 19) { lhs = W_ee + (s - 16) * 128; off = 128; }
            else if (s < 22) { lhs = W_ee + (s - 19) * 128; off = 256; }
            else if (s == 22){ lhs = b_en;                  off = 0;   }
            else if (s == 23){ lhs = b_ee;                  off = 128; }
            else             { lhs = b_ee;                  off = 256; }
            float a = 0.f;
            const int l0 = lh * 32;
#pragma unroll
            for (int u = 0; u < 32; ++u)
                a += lhs[l0 + u] * W1[(off + l0 + u) * 128 + k];
            __syncthreads();
            red[tid] = a;
            __syncthreads();
            if (lh == 0) {
                float val = red[k] + red[k + 128] + red[k + 256] + red[k + 384];
                if (s == 22) {
                    val += b1[k];
#pragma unroll
                    for (int j = 0; j < 8; ++j)
                        val += g[j] * W1[(384 + j) * 128 + k];
                }
                consts[k * 32 + s] = val;
            }
        } else {  // s == 25: consts[k][25] = W2[k][:] . W_dn; also store c_node
            float a = 0.f;
            const int j0 = lh * 32;
#pragma unroll
            for (int u = 0; u < 32; ++u)
                a += W2[k * 128 + j0 + u] * W_dn[j0 + u];
            __syncthreads();
            red[tid] = a;
            __syncthreads();
            if (lh == 0) {
                consts[k * 32 + 25] = red[k] + red[k + 128] + red[k + 256] + red[k + 384];
                consts[k * 32 + 26] = c_node;   // node bias, read as cst[26]
                consts[k * 32 + 27] = 0.f;
            }
        }
    }

    // ---- edge decoder output, grid-stride ----
    for (int q = bid * 512 + tid; q < N_EDGES / 4; q += nblk * 512) {
        const int e4 = q * 4;
        const float4* ep = (const float4*)(edges + (size_t)e4 * 3);
        const float4 f0 = ep[0], f1 = ep[1], f2 = ep[2];
        float4 o;
        o.x = fmaf(f0.x, w0, fmaf(f0.y, w1, fmaf(f0.z, w2, cb)));
        o.y = fmaf(f0.w, w0, fmaf(f1.x, w1, fmaf(f1.y, w2, cb)));
        o.z = fmaf(f1.z, w0, fmaf(f1.w, w1, fmaf(f2.x, w2, cb)));
        o.w = fmaf(f2.y, w0, fmaf(f2.z, w1, fmaf(f2.w, w2, cb)));
        *(float4*)(out_edges + e4) = o;
    }

    if (nch <= 0) return;   // fallback path does aggregation elsewhere

    // ---- zero LDS accumulator ----
    __syncthreads();
    for (int i = tid; i < BINSZ; i += 512)
        acc4[i] = make_float4(0.f, 0.f, 0.f, 0.f);
    __syncthreads();

    // ---- binned aggregation (R0-proven inner loop, BINSZ=4096) ----
    const int chunk = bid / 26;
    const int binid = bid % 26;
    const bool is_s = binid < NBINS;
    const int bin   = is_s ? binid : binid - NBINS;
    const int lo    = bin * BINSZ;
    const int* __restrict__ idx = is_s ? senders : receivers;

    const int e_beg = chunk * ce;
    const int e_end = min(e_beg + ce, N_EDGES);
    const int STRIDE = 512 * 8;

    int e8 = e_beg + tid * 8;
    int4 ia = make_int4(-1, -1, -1, -1), ib = ia;
    if (e8 < e_end) {
        ia = *(const int4*)(idx + e8);
        ib = *(const int4*)(idx + e8 + 4);
    }
    while (e8 < e_end) {
        const int e8n = e8 + STRIDE;
        int4 ian = ia, ibn = ib;
        if (e8n < e_end) {                    // prefetch next iteration's indices
            ian = *(const int4*)(idx + e8n);
            ibn = *(const int4*)(idx + e8n + 4);
        }
        const unsigned d0 = (unsigned)(ia.x - lo), d1 = (unsigned)(ia.y - lo);
        const unsigned d2 = (unsigned)(ia.z - lo), d3 = (unsigned)(ia.w - lo);
        const unsigned d4 = (unsigned)(ib.x - lo), d5 = (unsigned)(ib.y - lo);
        const unsigned d6 = (unsigned)(ib.z - lo), d7 = (unsigned)(ib.w - lo);
        if ((d0 < BINSZ) | (d1 < BINSZ) | (d2 < BINSZ) | (d3 < BINSZ)) {
            const float4* ep = (const float4*)(edges + (size_t)e8 * 3);
            const float4 f0 = ep[0], f1 = ep[1], f2 = ep[2];
            if (d0 < BINSZ) {
                atomicAdd(&acc[d0 * 4 + 0], f0.x); atomicAdd(&acc[d0 * 4 + 1], f0.y);
                atomicAdd(&acc[d0 * 4 + 2], f0.z); atomicAdd(&acc[d0 * 4 + 3], 1.0f);
            }
            if (d1 < BINSZ) {
                atomicAdd(&acc[d1 * 4 + 0], f0.w); atomicAdd(&acc[d1 * 4 + 1], f1.x);
                atomicAdd(&acc[d1 * 4 + 2], f1.y); atomicAdd(&acc[d1 * 4 + 3], 1.0f);
            }
            if (d2 < BINSZ) {
                atomicAdd(&acc[d2 * 4 + 0], f1.z); atomicAdd(&acc[d2 * 4 + 1], f1.w);
                atomicAdd(&acc[d2 * 4 + 2], f2.x); atomicAdd(&acc[d2 * 4 + 3], 1.0f);
            }
            if (d3 < BINSZ) {
                atomicAdd(&acc[d3 * 4 + 0], f2.y); atomicAdd(&acc[d3 * 4 + 1], f2.z);
                atomicAdd(&acc[d3 * 4 + 2], f2.w); atomicAdd(&acc[d3 * 4 + 3], 1.0f);
            }
        }
        if ((d4 < BINSZ) | (d5 < BINSZ) | (d6 < BINSZ) | (d7 < BINSZ)) {
            const float4* ep = (const float4*)(edges + (size_t)e8 * 3 + 12);
            const float4 f0 = ep[0], f1 = ep[1], f2 = ep[2];
            if (d4 < BINSZ) {
                atomicAdd(&acc[d4 * 4 + 0], f0.x); atomicAdd(&acc[d4 * 4 + 1], f0.y);
                atomicAdd(&acc[d4 * 4 + 2], f0.z); atomicAdd(&acc[d4 * 4 + 3], 1.0f);
            }
            if (d5 < BINSZ) {
                atomicAdd(&acc[d5 * 4 + 0], f0.w); atomicAdd(&acc[d5 * 4 + 1], f1.x);
                atomicAdd(&acc[d5 * 4 + 2], f1.y); atomicAdd(&acc[d5 * 4 + 3], 1.0f);
            }
            if (d6 < BINSZ) {
                atomicAdd(&acc[d6 * 4 + 0], f1.z); atomicAdd(&acc[d6 * 4 + 1], f1.w);
                atomicAdd(&acc[d6 * 4 + 2], f2.x); atomicAdd(&acc[d6 * 4 + 3], 1.0f);
            }
            if (d7 < BINSZ) {
                atomicAdd(&acc[d7 * 4 + 0], f2.y); atomicAdd(&acc[d7 * 4 + 1], f2.z);
                atomicAdd(&acc[d7 * 4 + 2], f2.w); atomicAdd(&acc[d7 * 4 + 3], 1.0f);
            }
        }
        ia = ian; ib = ibn;
        e8 = e8n;
    }
    __syncthreads();

    // writeback (clamped: last bin overhangs N_NODES)
    {
        const int hi = min(BINSZ, N_NODES - lo);
        float* part_s = ws + PART_OFF;
        float* part_r = part_s + (size_t)nch * (N_NODES * 4);
        float* basep = (is_s ? part_s : part_r)
                     + (size_t)chunk * (N_NODES * 4) + (size_t)lo * 4;
        float4* dst = (float4*)basep;
        for (int i = tid; i < hi; i += 512)
            dst[i] = acc4[i];
    }
}

// ---- fallback path (tiny ws): global-atomic scatter into esr[node][8] ----
__global__ __launch_bounds__(256) void edge_kernel_atomic(
    const float* __restrict__ edges,
    const int*   __restrict__ senders,
    const int*   __restrict__ receivers,
    float* __restrict__ ws)
{
    const int e = blockIdx.x * 256 + threadIdx.x;
    if (e >= N_EDGES) return;
    const float e0 = edges[e * 3 + 0];
    const float e1 = edges[e * 3 + 1];
    const float e2 = edges[e * 3 + 2];
    const int s = senders[e];
    const int r = receivers[e];
    float* esr = ws + ESR_OFF;
    atomicAdd(&esr[s * 8 + 0], e0);
    atomicAdd(&esr[s * 8 + 1], e1);
    atomicAdd(&esr[s * 8 + 2], e2);
    atomicAdd(&esr[s * 8 + 3], 1.0f);
    atomicAdd(&esr[r * 8 + 4], e0);
    atomicAdd(&esr[r * 8 + 5], e1);
    atomicAdd(&esr[r * 8 + 6], e2);
    atomicAdd(&esr[r * 8 + 7], 1.0f);
}

// Node MLP (R3-proven). Consts read wave-uniform -> scalar s_load path.
__global__ __launch_bounds__(64) void node_kernel(
    const float* __restrict__ nodes,  // [N][16]
    const float* __restrict__ ws,
    const float* __restrict__ part_s,
    const float* __restrict__ part_r,
    float* __restrict__ out_nodes,    // d_out
    int nchunks)
{
    const int n = blockIdx.x * 64 + threadIdx.x;
    if (n >= N_NODES) return;

    const float4* np4 = (const float4*)(nodes + (size_t)n * 16);
    const float4 n0 = np4[0], n1 = np4[1], n2 = np4[2], n3 = np4[3];

    float4 es = make_float4(0.f, 0.f, 0.f, 0.f);
    float4 er = make_float4(0.f, 0.f, 0.f, 0.f);
    if (nchunks > 0) {
        for (int c = 0; c < nchunks; ++c) {
            const float4 a = *(const float4*)(part_s + (size_t)c * (N_NODES * 4) + (size_t)n * 4);
            const float4 b = *(const float4*)(part_r + (size_t)c * (N_NODES * 4) + (size_t)n * 4);
            es.x += a.x; es.y += a.y; es.z += a.z; es.w += a.w;
            er.x += b.x; er.y += b.y; er.z += b.z; er.w += b.w;
        }
    } else {
        const float4* p = (const float4*)(ws + ESR_OFF + (size_t)n * 8);
        es = p[0];
        er = p[1];
    }

    const float* cst = ws + CONSTS_OFF;  // wave-uniform reads below
    float acc = 0.f;
#pragma unroll 4
    for (int k = 0; k < 128; ++k) {
        const float4 m0 = *(const float4*)(cst + k * 32 + 0);
        const float4 m1 = *(const float4*)(cst + k * 32 + 4);
        const float4 m2 = *(const float4*)(cst + k * 32 + 8);
        const float4 m3 = *(const float4*)(cst + k * 32 + 12);
        const float4 q0 = *(const float4*)(cst + k * 32 + 16);
        const float4 q1 = *(const float4*)(cst + k * 32 + 20);
        const float4 q2 = *(const float4*)(cst + k * 32 + 24);
        float pre = q1.z
            + n0.x * m0.x + n0.y * m0.y + n0.z * m0.z + n0.w * m0.w
            + n1.x * m1.x + n1.y * m1.y + n1.z * m1.z + n1.w * m1.w
            + n2.x * m2.x + n2.y * m2.y + n2.z * m2.z + n2.w * m2.w
            + n3.x * m3.x + n3.y * m3.y + n3.z * m3.z + n3.w * m3.w
            + es.x * q0.x + es.y * q0.y + es.z * q0.z
            + er.x * q0.w + er.y * q1.x + er.z * q1.y
            + es.w * q1.w + er.w * q2.x;
        acc += fmaxf(pre, 0.f) * q2.y;
    }
    out_nodes[n] = acc + cst[26];   // consts[0*32+26] = c_node
}

extern "C" void kernel_launch(void* const* d_in, const int* in_sizes, int n_in,
                              void* d_out, int out_size, void* d_ws, size_t ws_size,
                              hipStream_t stream) {
    const float* nodes     = (const float*)d_in[0];
    const float* edges     = (const float*)d_in[1];
    const float* globals_  = (const float*)d_in[2];
    const int*   senders   = (const int*)d_in[3];
    const int*   receivers = (const int*)d_in[4];
    const float* W_en = (const float*)d_in[5];
    const float* b_en = (const float*)d_in[6];
    const float* W_ee = (const float*)d_in[7];
    const float* b_ee = (const float*)d_in[8];
    const float* W1   = (const float*)d_in[9];
    const float* b1   = (const float*)d_in[10];
    const float* W2   = (const float*)d_in[11];
    const float* b2   = (const float*)d_in[12];
    const float* W_dn = (const float*)d_in[13];
    const float* b_dn = (const float*)d_in[14];
    const float* W_de = (const float*)d_in[15];
    const float* b_de = (const float*)d_in[16];

    float* ws  = (float*)d_ws;
    float* out = (float*)d_out;
    float* out_edges = out + N_NODES;

    long ws_floats = (long)(ws_size / 4);
    long per_chunk = 2L * N_NODES * 4;
    long avail = (ws_floats - PART_OFF) / per_chunk;
    int nch = (int)(avail < 1 ? 0 : (avail > MAXCH ? MAXCH : avail));

    float* part_s = ws + PART_OFF;
    float* part_r = part_s + (size_t)(nch > 0 ? nch : 1) * (N_NODES * 4);

    int ce = (N_EDGES + (nch > 0 ? nch : 1) - 1) / (nch > 0 ? nch : 1);
    ce = (ce + 7) & ~7;   // keep 8-edge groups int4-aligned

    front_kernel<<<26 * (nch > 0 ? nch : 1), 512, 0, stream>>>(
        edges, globals_, senders, receivers,
        W_en, b_en, W_ee, b_ee, W1, b1, W2, b2,
        W_dn, b_dn, W_de, b_de, ws, out_edges, nch, ce);

    if (nch < 1) {
        hipMemsetAsync(ws + ESR_OFF, 0, (size_t)N_NODES * 8 * sizeof(float), stream);
        edge_kernel_atomic<<<(N_EDGES + 255) / 256, 256, 0, stream>>>(
            edges, senders, receivers, ws);
    }

    node_kernel<<<(N_NODES + 63) / 64, 64, 0, stream>>>(
        nodes, ws, part_s, part_r, out, nch);
}